// Round 1
// baseline (154.836 us; speedup 1.0000x reference)
//
#include <hip/hip_runtime.h>
#include <hip/hip_bf16.h>

// EdgeDecoder: out[e] = W2 @ relu(W1 @ [z[src]; z[dst]] + b1) + b2
// Restructure: W1 = [W1a | W1b] over the concat ->
//   U[n] = W1a @ z[n], V[n] = W1b @ z[n]  (precomputed via MFMA)
//   out[e] = dot(relu(U[src]+V[dst]+b1), W2) + b2
//
// R8: phase 2 (edge_decode) is ~115us of the 137us: 327 MB of random 256B
// U/V row gathers over a 25.6 MB table => ~84% L2 miss, L3 random-gather
// bound (~2.9 TB/s effective). Avg degree 12.8 => 13x reuse is available
// but random order wastes it. Fix: counting-sort edges by 8-bit key
// (dst/6250 -> XCD bucket, src/1563 -> sb bucket). With blockIdx%8 ~ XCD:
// each XCD's V-partition (1.6 MB) is L2-resident, U swept in 400 KB
// sb-windows (blocks stride the sorted range so the concurrent window is
// ~20% => live set ~4 MB ~ L2). Sort = memset + hist + scan + scatter
// (~10us); decode writes out[eid] scattered 4B. Predicted total ~75us.

#define N_NODES 50000
#define N_EDGES 640000
#define H 128

#define NBINS 256     // 8 dst-XCD buckets x 32 src buckets
#define S1_BLOCKS 128 // hist/scatter grid
#define EPT 20        // edges per thread in hist/scatter (128*256*20 >= 640k)
#define P_XCD 64      // decode blocks per XCD (grid = 512)

using bf16 = __hip_bfloat16;
typedef __attribute__((ext_vector_type(8))) short short8;  // 8 bf16, 4 VGPRs
typedef __attribute__((ext_vector_type(4))) float f32x4;   // MFMA acc

#define GLD_LDS16(g, l)                                                     \
  __builtin_amdgcn_global_load_lds(                                         \
      (const __attribute__((address_space(1))) void*)(g),                   \
      (__attribute__((address_space(3))) void*)(l), 16, 0, 0)

static __device__ __forceinline__ short bfbits(float x) {
  __hip_bfloat16 h = __float2bfloat16(x);
  return *reinterpret_cast<short*>(&h);
}

static __device__ __forceinline__ short8 pack8(float4 a, float4 b) {
  short8 r;
  r[0] = bfbits(a.x); r[1] = bfbits(a.y); r[2] = bfbits(a.z); r[3] = bfbits(a.w);
  r[4] = bfbits(b.x); r[5] = bfbits(b.y); r[6] = bfbits(b.z); r[7] = bfbits(b.w);
  return r;
}

// Tiny: Wb[o][k] (bf16, A-frag row layout) from fp32 W1. o<128 -> W1[o][k],
// o>=128 -> W1[o-128][128+k]. 4096 units of 8 elems -> 16 blocks.
__global__ __launch_bounds__(256) void w_to_bf16(const float* __restrict__ W1,
                                                 bf16* __restrict__ Wb) {
  const int u = blockIdx.x * 256 + threadIdx.x;
  const int o = u >> 4, k8 = (u & 15) * 8;
  const float4* src = reinterpret_cast<const float4*>(
      W1 + (size_t)(o & (H - 1)) * (2 * H) + (o >> 7) * H + k8);
  *reinterpret_cast<short8*>(Wb + (size_t)o * H + k8) = pack8(src[0], src[1]);
}

#define HP 136  // padded bf16 LDS row stride (272B): breaks 256B-stride conflicts

// Phase 1: block = 4 waves = one 32-node tile; wave s owns outputs
// [s*64, s*64+64). fp32 z staged via global_load_lds DMA (no VGPRs), one
// LDS pass converts to bf16 tile, frags via ds_read_b128, 32 MFMAs, then
// LDS-transposed coalesced epilogue (reusing the fp32 stage buffer).
__global__ __launch_bounds__(256) void precompute_uv(
    const float* __restrict__ z, const bf16* __restrict__ Wb,
    bf16* __restrict__ U, bf16* __restrict__ V) {
  __shared__ float ldsF[32 * H];       // 16 KB: fp32 z stage, later epilogue tile
  __shared__ bf16 ldsH[32 * HP];       // 8.5 KB: padded bf16 z tile
  const int tid = threadIdx.x;
  const int lane = tid & 63;
  const int s = tid >> 6;  // wave id = o-split 0..3
  const int l15 = lane & 15, quad = lane >> 4;
  const int nodebase = blockIdx.x * 32;

  // Stage: wave s DMAs rows [s*8, s*8+8) of the tile; 4 x 1KB contiguous.
  {
    int r0 = nodebase + s * 8;
    if (r0 > N_NODES - 8) r0 = N_NODES - 8;  // tail clamp (stores guarded)
    const float* gsrc = z + (size_t)r0 * H + lane * 4;
    float* ldst = ldsF + s * 8 * H;  // + lane*16B implicit
#pragma unroll
    for (int j = 0; j < 4; ++j) GLD_LDS16(gsrc + j * 256, ldst + j * 256);
  }

  // W-frags from global bf16 (64 KB, L2-hot) — overlaps the DMA.
  short8 wf[4][4];  // [o-tile][k-step]
#pragma unroll
  for (int t = 0; t < 4; ++t) {
    const bf16* wp = Wb + (size_t)(s * 64 + t * 16 + l15) * H + quad * 8;
#pragma unroll
    for (int q = 0; q < 4; ++q)
      wf[t][q] = *reinterpret_cast<const short8*>(wp + q * 32);
  }

  __syncthreads();  // DMA + conversion-input visible

  // Convert: thread handles 16 consecutive fp32 of row (tid>>3).
  {
    const int row = tid >> 3, off = (tid & 7) * 16;
    const float4* fp = reinterpret_cast<const float4*>(ldsF + row * H + off);
    const float4 a = fp[0], b = fp[1], c = fp[2], d = fp[3];
    *reinterpret_cast<short8*>(&ldsH[row * HP + off]) = pack8(a, b);
    *reinterpret_cast<short8*>(&ldsH[row * HP + off + 8]) = pack8(c, d);
  }
  __syncthreads();

  // z-frags from LDS + 32 back-to-back MFMAs.
  short8 zf[2][4];
#pragma unroll
  for (int m = 0; m < 2; ++m)
#pragma unroll
    for (int q = 0; q < 4; ++q)
      zf[m][q] = *reinterpret_cast<const short8*>(
          &ldsH[(m * 16 + l15) * HP + quad * 8 + q * 32]);

  f32x4 acc[2][4] = {};
#pragma unroll
  for (int m = 0; m < 2; ++m)
#pragma unroll
    for (int t = 0; t < 4; ++t)
#pragma unroll
      for (int q = 0; q < 4; ++q)
        acc[m][t] =
            __builtin_amdgcn_mfma_f32_16x16x32_bf16(wf[t][q], zf[m][q], acc[m][t], 0, 0, 0);

  // Epilogue 1: acc -> LDS (reuse ldsF as 32 x 256 bf16, no pad). C/D layout:
  // col=l15 -> node row nl, row=quad*4+reg -> output o.
  bf16* epi = reinterpret_cast<bf16*>(ldsF);
#pragma unroll
  for (int m = 0; m < 2; ++m) {
    const int nl = m * 16 + l15;
#pragma unroll
    for (int t = 0; t < 4; ++t) {
      const int o = s * 64 + t * 16 + quad * 4;
      ushort4 st;
      st.x = (unsigned short)bfbits(acc[m][t][0]);
      st.y = (unsigned short)bfbits(acc[m][t][1]);
      st.z = (unsigned short)bfbits(acc[m][t][2]);
      st.w = (unsigned short)bfbits(acc[m][t][3]);
      *reinterpret_cast<ushort4*>(epi + nl * 256 + o) = st;
    }
  }
  __syncthreads();

  // Epilogue 2: coalesced stores; each instr = 4 node-rows x 256B contiguous.
#pragma unroll
  for (int half = 0; half < 2; ++half) {
    bf16* base = half ? V : U;
#pragma unroll
    for (int it = 0; it < 2; ++it) {
      const int nl = s * 8 + it * 4 + (lane >> 4);
      const int oc = (lane & 15) * 8;
      const short8 v = *reinterpret_cast<const short8*>(epi + nl * 256 + half * H + oc);
      const int n = nodebase + nl;
      if (n < N_NODES)
        *reinterpret_cast<short8*>(base + (size_t)n * H + oc) = v;
    }
  }
}

// ---------------- edge counting sort: key = (dst/6250)*32 + src/1563 -------

static __device__ __forceinline__ int edge_key(int src, int dst) {
  return (dst / 6250) * 32 + src / 1563;  // 8 XCD buckets x 32 src buckets
}

// S1: per-block LDS histogram -> one global atomicAdd per (block,bin).
// hist is padded x16 ints (64 B/bin) so per-bin atomics don't share lines.
__global__ __launch_bounds__(256) void edge_hist(const int* __restrict__ eidx,
                                                 int* __restrict__ hist) {
  __shared__ int lh[NBINS];
  const int t = threadIdx.x;
  lh[t] = 0;
  __syncthreads();
  const int base = blockIdx.x * (256 * EPT) + t;
#pragma unroll
  for (int j = 0; j < EPT; ++j) {
    const int e = base + j * 256;
    if (e < N_EDGES)
      atomicAdd(&lh[edge_key(eidx[e], eidx[N_EDGES + e])], 1);
  }
  __syncthreads();
  if (lh[t]) atomicAdd(&hist[t * 16], lh[t]);
}

// S2: exclusive scan of 256 bins -> cursors (padded) + xstart[9] (per-XCD).
__global__ __launch_bounds__(256) void edge_scan(const int* __restrict__ hist,
                                                 int* __restrict__ cursors,
                                                 int* __restrict__ xstart) {
  __shared__ int sh[NBINS];
  const int t = threadIdx.x;
  const int v = hist[t * 16];
  int acc = v;
  sh[t] = acc;
  for (int off = 1; off < NBINS; off <<= 1) {
    __syncthreads();
    const int add = (t >= off) ? sh[t - off] : 0;
    __syncthreads();
    acc += add;
    sh[t] = acc;
  }
  const int excl = acc - v;
  cursors[t * 16] = excl;
  if ((t & 31) == 0) xstart[t >> 5] = excl;
  if (t == 0) xstart[8] = N_EDGES;
}

// S3: scatter. Block-aggregated: LDS count -> one global reserve per bin ->
// per-edge LDS cursor. Packs (eid<<32 | dst<<16 | src) into one u64
// (src,dst < 65536). Within-bin order nondeterministic: harmless, each edge
// is computed once and written to out[eid].
__global__ __launch_bounds__(256) void edge_scatter(
    const int* __restrict__ eidx, int* __restrict__ cursors,
    unsigned long long* __restrict__ sde) {
  __shared__ int lh[NBINS];
  __shared__ int lcur[NBINS];
  const int t = threadIdx.x;
  lh[t] = 0;
  __syncthreads();
  int src[EPT], dst[EPT], key[EPT];
  const int base = blockIdx.x * (256 * EPT) + t;
#pragma unroll
  for (int j = 0; j < EPT; ++j) {
    const int e = base + j * 256;
    if (e < N_EDGES) {
      src[j] = eidx[e];
      dst[j] = eidx[N_EDGES + e];
      key[j] = edge_key(src[j], dst[j]);
      atomicAdd(&lh[key[j]], 1);
    } else {
      key[j] = -1;
    }
  }
  __syncthreads();
  lcur[t] = lh[t] ? atomicAdd(&cursors[t * 16], lh[t]) : 0;
  __syncthreads();
#pragma unroll
  for (int j = 0; j < EPT; ++j) {
    if (key[j] >= 0) {
      const int pos = atomicAdd(&lcur[key[j]], 1);
      sde[pos] = ((unsigned long long)(unsigned)(base + j * 256) << 32) |
                 ((unsigned)dst[j] << 16) | (unsigned)src[j];
    }
  }
}

static __device__ __forceinline__ void acc2(unsigned u, unsigned v,
                                            float b1lo, float b1hi,
                                            float w2lo, float w2hi, float& sum) {
  const float ulo = __uint_as_float(u << 16);
  const float uhi = __uint_as_float(u & 0xffff0000u);
  const float vlo = __uint_as_float(v << 16);
  const float vhi = __uint_as_float(v & 0xffff0000u);
  float h0 = ulo + vlo + b1lo; h0 = fmaxf(h0, 0.f);
  float h1 = uhi + vhi + b1hi; h1 = fmaxf(h1, 0.f);
  sum = fmaf(h0, w2lo, sum);
  sum = fmaf(h1, w2hi, sum);
}

// Phase 2 (sorted): block bid -> xcd = bid&7 (round-robin XCD dispatch),
// slot = bid>>3. XCD x owns sorted range [xstart[x], xstart[x+1]) whose dst
// all fall in its 1.6 MB V-partition (L2-resident). Blocks grid-stride the
// range so concurrent blocks cover a contiguous ~16k-edge window of the
// src-bucket sweep (live U window ~2.6 MB). 8-lane group per edge; gathers
// batched 4 edges deep. Result scattered to out[eid].
__global__ __launch_bounds__(256, 4) void edge_decode_sorted(
    const unsigned long long* __restrict__ sde, const bf16* __restrict__ Ub,
    const bf16* __restrict__ Vb, const float* __restrict__ bias1,
    const float* __restrict__ W2, const float* __restrict__ bias2,
    const int* __restrict__ xstart, float* __restrict__ out) {
  const int lane = threadIdx.x & 63;
  const int e8 = lane & 7;

  float b1r[16], w2r[16];
  const float4* bp = reinterpret_cast<const float4*>(bias1 + e8 * 16);
  const float4* wp = reinterpret_cast<const float4*>(W2 + e8 * 16);
#pragma unroll
  for (int q = 0; q < 4; ++q) {
    const float4 b = bp[q], wv = wp[q];
    b1r[q * 4 + 0] = b.x; b1r[q * 4 + 1] = b.y; b1r[q * 4 + 2] = b.z; b1r[q * 4 + 3] = b.w;
    w2r[q * 4 + 0] = wv.x; w2r[q * 4 + 1] = wv.y; w2r[q * 4 + 2] = wv.z; w2r[q * 4 + 3] = wv.w;
  }
  const float b2 = bias2[0];

  const int xcd = blockIdx.x & 7;
  const int slot = blockIdx.x >> 3;
  const int xs = xstart[xcd], xe = xstart[xcd + 1];
  const uint4* U4 = reinterpret_cast<const uint4*>(Ub);  // row = 16 uint4
  const uint4* V4 = reinterpret_cast<const uint4*>(Vb);

  for (int cb = xs + (slot * 4 + (int)(threadIdx.x >> 6)) * 64; cb < xe;
       cb += P_XCD * 256) {
    const int idx = cb + lane;
    const bool valid = idx < xe;
    const unsigned long long v = valid ? sde[idx] : 0ull;
    const int src = (int)(v & 0xFFFFu);
    const int dst = (int)((v >> 16) & 0xFFFFu);
    const int eid = (int)(v >> 32);

    float res = 0.f;
#pragma unroll
    for (int half = 0; half < 2; ++half) {
      uint4 ua[4], ub[4], va[4], vb[4];
      // Issue all 16 gather loads for 4 edges before any compute.
#pragma unroll
      for (int j = 0; j < 4; ++j) {
        const int i = half * 4 + j;
        const int sl = (lane & 56) + i;
        const int s_i = __shfl(src, sl);
        const int d_i = __shfl(dst, sl);
        const uint4* up = U4 + (size_t)s_i * 16 + e8 * 2;
        const uint4* vp = V4 + (size_t)d_i * 16 + e8 * 2;
        ua[j] = up[0]; ub[j] = up[1];
        va[j] = vp[0]; vb[j] = vp[1];
      }
#pragma unroll
      for (int j = 0; j < 4; ++j) {
        const int i = half * 4 + j;
        float sum = 0.f;
        acc2(ua[j].x, va[j].x, b1r[0],  b1r[1],  w2r[0],  w2r[1],  sum);
        acc2(ua[j].y, va[j].y, b1r[2],  b1r[3],  w2r[2],  w2r[3],  sum);
        acc2(ua[j].z, va[j].z, b1r[4],  b1r[5],  w2r[4],  w2r[5],  sum);
        acc2(ua[j].w, va[j].w, b1r[6],  b1r[7],  w2r[6],  w2r[7],  sum);
        acc2(ub[j].x, vb[j].x, b1r[8],  b1r[9],  w2r[8],  w2r[9],  sum);
        acc2(ub[j].y, vb[j].y, b1r[10], b1r[11], w2r[10], w2r[11], sum);
        acc2(ub[j].z, vb[j].z, b1r[12], b1r[13], w2r[12], w2r[13], sum);
        acc2(ub[j].w, vb[j].w, b1r[14], b1r[15], w2r[14], w2r[15], sum);
        sum += __shfl_xor(sum, 1);
        sum += __shfl_xor(sum, 2);
        sum += __shfl_xor(sum, 4);
        if (e8 == i) res = sum + b2;
      }
    }
    if (valid) out[eid] = res;  // scattered 4 B store via edge id
  }
}

extern "C" void kernel_launch(void* const* d_in, const int* in_sizes, int n_in,
                              void* d_out, int out_size, void* d_ws, size_t ws_size,
                              hipStream_t stream) {
  const float* z     = (const float*)d_in[0];
  const float* W1    = (const float*)d_in[1];
  const float* bias1 = (const float*)d_in[2];
  const float* W2    = (const float*)d_in[3];
  const float* bias2 = (const float*)d_in[4];
  const int*   eidx  = (const int*)d_in[5];
  float* out = (float*)d_out;

  bf16* U  = (bf16*)d_ws;                               // [N_NODES, H]
  bf16* V  = U + (size_t)N_NODES * H;                   // [N_NODES, H]
  bf16* Wb = V + (size_t)N_NODES * H;                   // [256, H] (64 KB)
  unsigned long long* sde = (unsigned long long*)(Wb + 256 * H);  // [N_EDGES]
  int* hist    = (int*)(sde + N_EDGES);                 // NBINS x16 padded
  int* cursors = hist + NBINS * 16;                     // NBINS x16 padded
  int* xstart  = cursors + NBINS * 16;                  // [9]

  // Sort state rebuilt every launch (ws is poisoned between iterations).
  hipMemsetAsync(hist, 0, NBINS * 16 * sizeof(int), stream);

  // W convert: 4096 units / 256 = 16 blocks (~1.5 us).
  hipLaunchKernelGGL(w_to_bf16, dim3(16), dim3(256), 0, stream, W1, Wb);
  // Phase 1: 1563 blocks x 4 waves; block = 32-node tile, wave = 64-output split.
  hipLaunchKernelGGL(precompute_uv, dim3((N_NODES + 31) / 32), dim3(256), 0, stream,
                     z, Wb, U, V);
  // Edge counting sort: hist -> scan -> scatter (~10 us total).
  hipLaunchKernelGGL(edge_hist, dim3(S1_BLOCKS), dim3(256), 0, stream, eidx, hist);
  hipLaunchKernelGGL(edge_scan, dim3(1), dim3(256), 0, stream, hist, cursors, xstart);
  hipLaunchKernelGGL(edge_scatter, dim3(S1_BLOCKS), dim3(256), 0, stream,
                     eidx, cursors, sde);
  // Phase 2: 512 blocks (64/XCD), grid-striding each XCD's sorted range.
  hipLaunchKernelGGL(edge_decode_sorted, dim3(8 * P_XCD), dim3(256), 0, stream,
                     sde, U, V, bias1, W2, bias2, xstart, out);
}